// Round 4
// baseline (936.996 us; speedup 1.0000x reference)
//
#include <hip/hip_runtime.h>
#include <math.h>

// clDice loss via register-resident temporal cascade (float2 lanes).
// All 10 soft_skel iterations run as a systolic pipeline of erode stages,
// swept top->bottom. Per lane: 2 columns (float2), per stage a 3-row rolling
// register window. No LDS, no barriers; horizontal halo via DPP wave shifts.
// R6: min/max trees as single VOP3 v_min3_f32/v_max3_f32.
// R7: 6 row-strips x 960 blocks (tail fix): 510us, VALUBusy 69%. BEST so far.
// R8 (reverted): LDS ring + x5 unroll + launch_bounds(256,5) -> E[11][3]
//   demoted to scratch (WRITE_SIZE 240KB->87MB), 734us.
// R9 (reverted): warmup/steady/drain split, unfenced -> scheduler stretched
//   live ranges across D/E and across the 3 unrolled steps, spilled the
//   cascade (WRITE_SIZE 1.03GB, FETCH 2.2x), 731us. Split never got tested.
// R10: R9 split + sched_barrier(0) fences at step seams (after oring loads,
//   after Pass D, after Pass E). Scheduler may interleave the 10 independent
//   D-stages (the ILP target: hides DPP wait-states + min/max chains) but
//   cannot rename-interleave D with E or pipeline across steps -> live
//   ranges stay R7-sized. Loads still issue early in program order; fences
//   don't force waitcnt, so prefetch latency hiding is intact.
//
// Geometry: wave covers 128 cols (lane*2 + 104*s - 12), owns 104 [104s,..).
// 10 col-strips x 6 row-strips(171 rows, 11-row warmup / 12-row drain)
// x 64 jobs (= 2 tensors x 16 batch x 2 ch) = 3840 waves = 960 blocks.

#define HH 1024
#define WW 1024
#define OWN_W 104
#define SROWS 171   // row strip height; y0 = v*171, last strip = 169 rows
#define NMACRO 65   // 195 steps = 171 + 11 warmup + 12 drain + 1 pad
#define MWARM 8     // macros 0..7 (steps 0..23, r <= y0+12) guarded

#define MOD3(x) ((((x) % 3) + 3) % 3)
#define SFENCE __builtin_amdgcn_sched_barrier(0)

__device__ __forceinline__ float2 f2s(float v) { float2 r; r.x = v; r.y = v; return r; }
__device__ __forceinline__ float sigm(float x) { return __builtin_amdgcn_rcpf(1.0f + __expf(-x)); }

// single-instruction VOP3 3-operand min/max (no IEEE canonicalize padding)
__device__ __forceinline__ float vmin3(float a, float b, float c) {
    float d; asm("v_min3_f32 %0, %1, %2, %3" : "=v"(d) : "v"(a), "v"(b), "v"(c)); return d;
}
__device__ __forceinline__ float vmax3(float a, float b, float c) {
    float d; asm("v_max3_f32 %0, %1, %2, %3" : "=v"(d) : "v"(a), "v"(b), "v"(c)); return d;
}
__device__ __forceinline__ float vmax(float a, float b) {
    float d; asm("v_max_f32 %0, %1, %2" : "=v"(d) : "v"(a), "v"(b)); return d;
}
__device__ __forceinline__ float relu(float x) {
    float d; asm("v_max_f32 %0, 0, %1" : "=v"(d) : "v"(x)); return d;
}
__device__ __forceinline__ float min5(float a, float b, float c, float d, float e) {
    return vmin3(vmin3(a, b, c), d, e);
}

// lane i <- lane i-1 across the full wave (== __shfl_up(x,1,64)); lane 0 keeps own.
__device__ __forceinline__ float dpp_up1(float x) {
    int i = __builtin_bit_cast(int, x);
    int r = __builtin_amdgcn_update_dpp(i, i, 0x138, 0xf, 0xf, false);  // wave_shr:1
    return __builtin_bit_cast(float, r);
}
// lane i <- lane i+1 across the full wave (== __shfl_down(x,1,64)); lane 63 keeps own.
__device__ __forceinline__ float dpp_dn1(float x) {
    int i = __builtin_bit_cast(int, x);
    int r = __builtin_amdgcn_update_dpp(i, i, 0x130, 0xf, 0xf, false);  // wave_shl:1
    return __builtin_bit_cast(float, r);
}

// One macro iteration (3 steps). STEADY_ is a literal 0/1; all STEADY_-guarded
// branches fold at compile time. Textual expansion (no lambda captures around
// the E/oring aggregates -- see R8 post-mortem). SFENCE at the D/E seams caps
// the scheduling window so live ranges stay small (R9 post-mortem).
#define RUN_MACRO(STEADY_)                                                      \
  {                                                                             \
    _Pragma("unroll")                                                           \
    for (int j = 0; j < 12; ++j) oring[j] = oring[j + 3];                       \
    _Pragma("unroll")                                                           \
    for (int j = 0; j < 3; ++j) {                                               \
      const int orow = rBase + 3 * m + j;                                       \
      oring[12 + j] = STEADY_ ? loadOtherFast(orow) : loadOther(orow);          \
    }                                                                           \
    SFENCE;                                                                     \
    _Pragma("unroll")                                                           \
    for (int p = 0; p < 3; ++p) {                                               \
      const int r = rBase + 3 * m + p;                                          \
      const float2 img = nextImg;                                               \
      nextImg = STEADY_ ? loadImgFast(r + 1) : loadImg(r + 1);                  \
      /* -------- Pass D: dilate stage k at row yd = r-k-2 -------- */          \
      _Pragma("unroll")                                                         \
      for (int k = 1; k <= 10; ++k) {                                           \
        const int yd = r - k - 2;                                               \
        if (STEADY_ || (yd >= y0 && yd < yHi)) {                                \
          const float2 a = E[k][MOD3(p - k)];       /* row yd-1 */              \
          const float2 b = E[k][MOD3(p - k + 1)];   /* row yd   */              \
          const float2 c = E[k][MOD3(p - k + 2)];   /* row yd+1 */              \
          float2 vm;                                                            \
          if (!STEADY_ && yd == 0) {                /* top: exclude row -1 */   \
            vm.x = vmax(b.x, c.x); vm.y = vmax(b.y, c.y);                       \
          } else if (!STEADY_ && yd == HH - 1) {    /* bottom: excl row 1024 */ \
            vm.x = vmax(a.x, b.x); vm.y = vmax(a.y, b.y);                       \
          } else {                                                              \
            vm.x = vmax3(a.x, b.x, c.x); vm.y = vmax3(a.y, b.y, c.y);           \
          }                                                                     \
          if (sEdge) { if (colOOB) vm = f2s(-INFINITY); }                       \
          const float vl = dpp_up1(vm.y);                                       \
          const float vr = dpp_dn1(vm.x);                                       \
          float2 h;                                                             \
          h.x = vmax3(vl,   vm.x, vm.y);                                        \
          h.y = vmax3(vm.x, vm.y, vr);                                          \
          const float2 io = E[k - 1][MOD3(p - k + 1)];  /* img_k at row yd */   \
          float2 ct;                                                            \
          ct.x = relu(io.x - h.x);                                              \
          ct.y = relu(io.y - h.y);                                              \
          const float2 ot = oring[10 + p - k];                                  \
          sumS.x += ct.x; sumS.y += ct.y;                                       \
          sumP.x = fmaf(ot.x, ct.x, sumP.x);                                    \
          sumP.y = fmaf(ot.y, ct.y, sumP.y);                                    \
        }                                                                       \
      }                                                                         \
      SFENCE;                                                                   \
      /* -------- Pass E: erode cascade, stage k emits row r-k -------- */      \
      E[0][MOD3(p)] = img;                                                      \
      float2 np_ = img;                                                         \
      _Pragma("unroll")                                                         \
      for (int k = 1; k <= 10; ++k) {                                           \
        const float2 A = E[k - 1][MOD3(p - k + 2)];  /* row r-k-1 (up) */       \
        const float2 B = E[k - 1][MOD3(p - k)];      /* row r-k   (center) */   \
        const float2 C = np_;                        /* row r-k+1 (down) */     \
        const float bl = dpp_up1(B.y);                                          \
        const float br = dpp_dn1(B.x);                                          \
        float2 ne;                                                              \
        ne.x = min5(A.x, C.x, bl,  B.y, B.x);                                   \
        ne.y = min5(A.y, C.y, B.x, br,  B.y);                                   \
        if (!STEADY_) {                                                         \
          const int yN = r - k;                                                 \
          if ((unsigned)yN >= HH) ne = f2s(INFINITY);                           \
          else if (sEdge && colOOB) ne = f2s(INFINITY);                         \
        } else {                                                                \
          if (sEdge && colOOB) ne = f2s(INFINITY);                              \
        }                                                                       \
        E[k][MOD3(p - k)] = ne;                                                 \
        np_ = ne;                                                               \
      }                                                                         \
      SFENCE;                                                                   \
    }                                                                           \
  }

__global__ __launch_bounds__(256, 4)
void skel_kernel(const float* __restrict__ logits,
                 const float* __restrict__ targets,
                 float* __restrict__ sums)
{
    const int lane = threadIdx.x & 63;
    const int gwid = __builtin_amdgcn_readfirstlane(blockIdx.x * 4 + (threadIdx.x >> 6));
    const int job  = gwid / 60;          // 0..63
    const int rem  = gwid - job * 60;
    const int s    = rem % 10;           // col strip 0..9
    const int v    = rem / 10;           // row strip 0..5
    const int tensor = job >> 5;         // 0: skel(pred), 1: skel(target)
    const int plane  = job & 31;
    const size_t planeOff = (size_t)plane * (HH * WW);
    const float* __restrict__ src  = tensor ? targets : logits;   // skel source
    const float* __restrict__ osrc = tensor ? logits  : targets;  // multiplied tensor
    const bool sEdge = (s == 0) || (s == 9);

    const int colBase = OWN_W * s - 12 + lane * 2;
    const bool colOOB = (colBase < 0) || (colBase > WW - 2);      // whole-lane (even boundaries)
    const int colC = colBase < 0 ? 0 : (colBase > WW - 2 ? WW - 2 : colBase);
    const int y0  = v * SROWS;
    const int yHi = (y0 + SROWS < HH) ? (y0 + SROWS) : HH;        // runtime strip end
    const int rBase = y0 - 11;

    // Steady macros m in [MWARM, mSteady): every step r = rBase+3m+p satisfies
    // r in [y0+13, min(yHi+1, HH-2)] -> D-guard always true, yd in [1,1022],
    // E rows in-image, loadImg(r+1) in-image, loadOther rows unclamped.
    const int rSteadyEnd = (yHi + 1 < HH - 2) ? (yHi + 1) : (HH - 2);
    const int mSteady = (rSteadyEnd - y0 + 9) / 3;   // 60 for v<=4, 58 for v=5

    const int ownHi = (OWN_W * (s + 1) < WW) ? OWN_W * (s + 1) : WW;
    const bool ownedLane = (colBase >= OWN_W * s) && (colBase < ownHi);

    // E[k][slot]: stage-k erode output, 3-row rolling window. Row y lives at
    // slot (y - rBase) mod 3 (stage-independent). E[0] = source image window.
    float2 E[11][3];
#pragma unroll
    for (int k = 0; k < 11; ++k)
#pragma unroll
        for (int j = 0; j < 3; ++j) E[k][j] = f2s(INFINITY);

    // shift-register ring of 'other' rows; at macro m, slot j holds row
    // (y0 - 23 + 3m + j). Stage k, phase p reads slot 10+p-k (row = dilate row).
    float2 oring[15];
#pragma unroll
    for (int j = 0; j < 15; ++j) oring[j] = f2s(0.f);

    float2 sumS = f2s(0.f), sumP = f2s(0.f);

    auto loadImg = [&](int row) -> float2 {
        float2 x;
        if ((unsigned)row < HH) {
            const float* p = src + planeOff + (size_t)row * WW + colC;
            x = *(const float2*)p;
            if (!tensor) { x.x = sigm(x.x); x.y = sigm(x.y); }
            if (sEdge && colOOB) x = f2s(INFINITY);
        } else {
            x = f2s(INFINITY);   // out-of-image rows: erode identity
        }
        return x;
    };
    auto loadImgFast = [&](int row) -> float2 {   // row statically in-image
        const float* p = src + planeOff + (size_t)row * WW + colC;
        float2 x = *(const float2*)p;
        if (!tensor) { x.x = sigm(x.x); x.y = sigm(x.y); }
        if (sEdge && colOOB) x = f2s(INFINITY);
        return x;
    };
    auto loadOther = [&](int row) -> float2 {
        int rc = row < 0 ? 0 : (row > HH - 1 ? HH - 1 : row);
        const float* p = osrc + planeOff + (size_t)rc * WW + colC;
        float2 x = *(const float2*)p;
        if (tensor) { x.x = sigm(x.x); x.y = sigm(x.y); }
        return x;
    };
    auto loadOtherFast = [&](int row) -> float2 {  // row statically in-image
        const float* p = osrc + planeOff + (size_t)row * WW + colC;
        float2 x = *(const float2*)p;
        if (tensor) { x.x = sigm(x.x); x.y = sigm(x.y); }
        return x;
    };

    float2 nextImg = loadImg(rBase);   // prefetch row for t=0

    // ---------------- warmup (guarded) ----------------
#pragma unroll 1
    for (int m = 0; m < MWARM; ++m) RUN_MACRO(0)

    // ---------------- steady (branch-free) ----------------
#pragma unroll 1
    for (int m = MWARM; m < mSteady; ++m) RUN_MACRO(1)

    // ---------------- drain (guarded) ----------------
#pragma unroll 1
    for (int m = mSteady; m < NMACRO; ++m) RUN_MACRO(0)

    // ---------- reduce: mask unowned lanes, wave-reduce, 2 atomics ----------
    if (!ownedLane) { sumS = f2s(0.f); sumP = f2s(0.f); }
    float aS = sumS.x + sumS.y;
    float aP = sumP.x + sumP.y;
#pragma unroll
    for (int off = 32; off > 0; off >>= 1) {
        aS += __shfl_down(aS, off, 64);
        aP += __shfl_down(aP, off, 64);
    }
    if (lane == 0) {
        const int base = plane * 4 + tensor * 2;
        atomicAdd(&sums[base],     aS);   // sum(skel)
        atomicAdd(&sums[base + 1], aP);   // sum(skel * other)
    }
}

__global__ void finalize_kernel(const float* __restrict__ s4, float* __restrict__ out)
{
    __shared__ float cl[32];
    int p = threadIdx.x;
    if (p < 32) {
        const float* s = s4 + p * 4;
        float tprec = s[1] / (s[0] + 1e-6f);
        float tsens = s[3] / (s[2] + 1e-6f);
        cl[p] = 2.f * tprec * tsens / (tprec + tsens + 1e-6f);
    }
    __syncthreads();
    if (p == 0) {
        float a = 0.f, vch = 0.f;
        for (int b = 0; b < 16; ++b) { a += cl[b * 2]; vch += cl[b * 2 + 1]; }
        out[0] = 1.f - 0.5f * (a / 16.f + vch / 16.f);
    }
}

extern "C" void kernel_launch(void* const* d_in, const int* in_sizes, int n_in,
                              void* d_out, int out_size, void* d_ws, size_t ws_size,
                              hipStream_t stream)
{
    const float* logits  = (const float*)d_in[0];
    const float* targets = (const float*)d_in[1];
    float* out  = (float*)d_out;
    float* sums = (float*)d_ws;

    hipMemsetAsync(d_ws, 0, 32 * 4 * sizeof(float), stream);

    // 3840 waves = 10 col-strips x 6 row-strips x 64 jobs; 4 waves per block.
    skel_kernel<<<960, 256, 0, stream>>>(logits, targets, sums);
    finalize_kernel<<<1, 64, 0, stream>>>(sums, out);
}

// Round 5
// 669.977 us; speedup vs baseline: 1.3985x; 1.3985x over previous
//
#include <hip/hip_runtime.h>
#include <math.h>

// clDice loss via register-resident temporal cascade (float2 lanes).
// All 10 soft_skel iterations run as a systolic pipeline of erode stages,
// swept top->bottom. Per lane: 2 columns (float2), per stage a 3-row rolling
// register window. No LDS, no barriers; horizontal halo via DPP wave shifts.
// R6: min/max trees as single VOP3 v_min3_f32/v_max3_f32.
// R7: 6 row-strips x 960 blocks: 510us, VALUBusy 69%, VGPR 60, no scratch.
// R8 (reverted): LDS ring + x5 unroll -> E demoted to scratch, 734us.
// R9 (reverted): warmup/steady/drain body triplication -> spill (1.03GB
//   scratch writes), 731us.
// R10 (reverted): R9 + sched_barrier fences -> STILL spilled (1.1GB) ->
//   spill is caused by body multiplication itself, not scheduling freedom.
//   LESSON: this kernel tolerates exactly ONE copy of the hot body.
// R11: back to exact R7 single-body structure; cut real VALU work with
//   CDNA packed FP32 (VOP3P). Per D-stage epilogue was 8 scalar VALU
//   (2 sub + 2 relu + 2 add + 2 fma); now 5 (pk_sub + 2 relu + pk_add +
//   pk_fma). min/max have no packed form, so the morphology core stays
//   scalar VOP3 min3/max3. Net: -30 VALU/step of ~230 (-13%).
//
// Geometry: wave covers 128 cols (lane*2 + 104*s - 12), owns 104 [104s,..).
// 10 col-strips x 6 row-strips(171 rows, 11-row warmup / 12-row drain)
// x 64 jobs (= 2 tensors x 16 batch x 2 ch) = 3840 waves = 960 blocks.

#define HH 1024
#define WW 1024
#define OWN_W 104
#define SROWS 171   // row strip height; y0 = v*171, last strip = 169 rows
#define NMACRO 65   // 195 steps = 171 + 11 warmup + 12 drain + 1 pad

#define MOD3(x) ((((x) % 3) + 3) % 3)

typedef float v2f __attribute__((ext_vector_type(2)));

__device__ __forceinline__ float2 f2s(float v) { float2 r; r.x = v; r.y = v; return r; }
__device__ __forceinline__ float sigm(float x) { return __builtin_amdgcn_rcpf(1.0f + __expf(-x)); }

// single-instruction VOP3 3-operand min/max (no IEEE canonicalize padding)
__device__ __forceinline__ float vmin3(float a, float b, float c) {
    float d; asm("v_min3_f32 %0, %1, %2, %3" : "=v"(d) : "v"(a), "v"(b), "v"(c)); return d;
}
__device__ __forceinline__ float vmax3(float a, float b, float c) {
    float d; asm("v_max3_f32 %0, %1, %2, %3" : "=v"(d) : "v"(a), "v"(b), "v"(c)); return d;
}
__device__ __forceinline__ float vmax(float a, float b) {
    float d; asm("v_max_f32 %0, %1, %2" : "=v"(d) : "v"(a), "v"(b)); return d;
}
__device__ __forceinline__ float relu(float x) {
    float d; asm("v_max_f32 %0, 0, %1" : "=v"(d) : "v"(x)); return d;
}
__device__ __forceinline__ float min5(float a, float b, float c, float d, float e) {
    return vmin3(vmin3(a, b, c), d, e);
}

// ---- VOP3P packed fp32: one instruction, two lanes of work ----
__device__ __forceinline__ float2 pk_sub(float2 a, float2 b) {   // a - b
    v2f av = {a.x, a.y}, bv = {b.x, b.y}, dv;
    asm("v_pk_add_f32 %0, %1, %2 neg_lo:[0,1] neg_hi:[0,1]"
        : "=v"(dv) : "v"(av), "v"(bv));
    float2 r; r.x = dv.x; r.y = dv.y; return r;
}
__device__ __forceinline__ float2 pk_add(float2 a, float2 b) {   // a + b
    v2f av = {a.x, a.y}, bv = {b.x, b.y}, dv;
    asm("v_pk_add_f32 %0, %1, %2" : "=v"(dv) : "v"(av), "v"(bv));
    float2 r; r.x = dv.x; r.y = dv.y; return r;
}
__device__ __forceinline__ float2 pk_fma(float2 a, float2 b, float2 c) {  // a*b + c
    v2f av = {a.x, a.y}, bv = {b.x, b.y}, cv = {c.x, c.y}, dv;
    asm("v_pk_fma_f32 %0, %1, %2, %3" : "=v"(dv) : "v"(av), "v"(bv), "v"(cv));
    float2 r; r.x = dv.x; r.y = dv.y; return r;
}

// lane i <- lane i-1 across the full wave (== __shfl_up(x,1,64)); lane 0 keeps own.
__device__ __forceinline__ float dpp_up1(float x) {
    int i = __builtin_bit_cast(int, x);
    int r = __builtin_amdgcn_update_dpp(i, i, 0x138, 0xf, 0xf, false);  // wave_shr:1
    return __builtin_bit_cast(float, r);
}
// lane i <- lane i+1 across the full wave (== __shfl_down(x,1,64)); lane 63 keeps own.
__device__ __forceinline__ float dpp_dn1(float x) {
    int i = __builtin_bit_cast(int, x);
    int r = __builtin_amdgcn_update_dpp(i, i, 0x130, 0xf, 0xf, false);  // wave_shl:1
    return __builtin_bit_cast(float, r);
}

__global__ __launch_bounds__(256, 4)
void skel_kernel(const float* __restrict__ logits,
                 const float* __restrict__ targets,
                 float* __restrict__ sums)
{
    const int lane = threadIdx.x & 63;
    const int gwid = __builtin_amdgcn_readfirstlane(blockIdx.x * 4 + (threadIdx.x >> 6));
    const int job  = gwid / 60;          // 0..63
    const int rem  = gwid - job * 60;
    const int s    = rem % 10;           // col strip 0..9
    const int v    = rem / 10;           // row strip 0..5
    const int tensor = job >> 5;         // 0: skel(pred), 1: skel(target)
    const int plane  = job & 31;
    const size_t planeOff = (size_t)plane * (HH * WW);
    const float* __restrict__ src  = tensor ? targets : logits;   // skel source
    const float* __restrict__ osrc = tensor ? logits  : targets;  // multiplied tensor
    const bool sEdge = (s == 0) || (s == 9);

    const int colBase = OWN_W * s - 12 + lane * 2;
    const bool colOOB = (colBase < 0) || (colBase > WW - 2);      // whole-lane (even boundaries)
    const int colC = colBase < 0 ? 0 : (colBase > WW - 2 ? WW - 2 : colBase);
    const int y0  = v * SROWS;
    const int yHi = (y0 + SROWS < HH) ? (y0 + SROWS) : HH;        // runtime strip end
    const int rBase = y0 - 11;

    const int ownHi = (OWN_W * (s + 1) < WW) ? OWN_W * (s + 1) : WW;
    const bool ownedLane = (colBase >= OWN_W * s) && (colBase < ownHi);

    // E[k][slot]: stage-k erode output, 3-row rolling window. Row y lives at
    // slot (y - rBase) mod 3 (stage-independent). E[0] = source image window.
    float2 E[11][3];
#pragma unroll
    for (int k = 0; k < 11; ++k)
#pragma unroll
        for (int j = 0; j < 3; ++j) E[k][j] = f2s(INFINITY);

    // shift-register ring of 'other' rows; at macro m, slot j holds row
    // (y0 - 23 + 3m + j). Stage k, phase p reads slot 10+p-k (row = dilate row).
    float2 oring[15];
#pragma unroll
    for (int j = 0; j < 15; ++j) oring[j] = f2s(0.f);

    float2 sumS = f2s(0.f), sumP = f2s(0.f);

    auto loadImg = [&](int row) -> float2 {
        float2 x;
        if ((unsigned)row < HH) {
            const float* p = src + planeOff + (size_t)row * WW + colC;
            x = *(const float2*)p;
            if (!tensor) { x.x = sigm(x.x); x.y = sigm(x.y); }
            if (sEdge && colOOB) x = f2s(INFINITY);
        } else {
            x = f2s(INFINITY);   // out-of-image rows: erode identity
        }
        return x;
    };
    auto loadOther = [&](int row) -> float2 {
        int rc = row < 0 ? 0 : (row > HH - 1 ? HH - 1 : row);
        const float* p = osrc + planeOff + (size_t)rc * WW + colC;
        float2 x = *(const float2*)p;
        if (tensor) { x.x = sigm(x.x); x.y = sigm(x.y); }
        return x;
    };

    float2 nextImg = loadImg(rBase);   // prefetch row for t=0

#pragma unroll 1
    for (int m = 0; m < NMACRO; ++m) {
        // ring shift + 3 new 'other' rows (consumed >=4 steps later)
#pragma unroll
        for (int j = 0; j < 12; ++j) oring[j] = oring[j + 3];
#pragma unroll
        for (int j = 0; j < 3; ++j) oring[12 + j] = loadOther(rBase + 3 * m + j);

#pragma unroll
        for (int p = 0; p < 3; ++p) {
            const int r = rBase + 3 * m + p;     // img row fed this step
            const float2 img = nextImg;
            nextImg = loadImg(r + 1);            // prefetch next step's row

            // ---------- Pass D: dilate stage k at row yd = r-k-2 (pre-update windows) ----------
#pragma unroll
            for (int k = 1; k <= 10; ++k) {
                const int yd = r - k - 2;
                if (yd >= y0 && yd < yHi) {             // wave-uniform ownership guard
                    const float2 a = E[k][MOD3(p - k)];       // row yd-1
                    const float2 b = E[k][MOD3(p - k + 1)];   // row yd
                    const float2 c = E[k][MOD3(p - k + 2)];   // row yd+1
                    float2 vm;
                    if (yd == 0) {                // image top: exclude row -1
                        vm.x = vmax(b.x, c.x); vm.y = vmax(b.y, c.y);
                    } else if (yd == HH - 1) {    // image bottom: exclude row 1024
                        vm.x = vmax(a.x, b.x); vm.y = vmax(a.y, b.y);
                    } else {
                        vm.x = vmax3(a.x, b.x, c.x); vm.y = vmax3(a.y, b.y, c.y);
                    }
                    if (sEdge) { if (colOOB) vm = f2s(-INFINITY); }  // col truncation at image edge
                    const float vl = dpp_up1(vm.y);
                    const float vr = dpp_dn1(vm.x);
                    float2 h;
                    h.x = vmax3(vl,   vm.x, vm.y);
                    h.y = vmax3(vm.x, vm.y, vr);
                    const float2 io = E[k - 1][MOD3(p - k + 1)];  // img_k at row yd
                    // packed epilogue: ct = relu(io - h); sumS += ct; sumP += ot*ct
                    const float2 d_ = pk_sub(io, h);
                    float2 ct;
                    ct.x = relu(d_.x);
                    ct.y = relu(d_.y);
                    const float2 ot = oring[10 + p - k];
                    sumS = pk_add(sumS, ct);
                    sumP = pk_fma(ot, ct, sumP);
                }
            }

            // ---------- Pass E: erode cascade, stage k emits row r-k ----------
            E[0][MOD3(p)] = img;
            float2 np_ = img;    // new row of stage k-1 (row r-k+1 when at stage k)
#pragma unroll
            for (int k = 1; k <= 10; ++k) {
                const float2 A = E[k - 1][MOD3(p - k + 2)];  // row r-k-1 (up)
                const float2 B = E[k - 1][MOD3(p - k)];      // row r-k   (center)
                const float2 C = np_;                        // row r-k+1 (down)
                const float bl = dpp_up1(B.y);
                const float br = dpp_dn1(B.x);
                float2 ne;
                ne.x = min5(A.x, C.x, bl,  B.y, B.x);
                ne.y = min5(A.y, C.y, B.x, br,  B.y);
                const int yN = r - k;
                if ((unsigned)yN >= HH) {        // out-of-image rows stay +inf
                    ne = f2s(INFINITY);
                } else if (sEdge) {
                    if (colOOB) ne = f2s(INFINITY);  // out-of-image cols stay +inf
                }
                E[k][MOD3(p - k)] = ne;
                np_ = ne;
            }
        }
    }

    // ---------- reduce: mask unowned lanes, wave-reduce, 2 atomics ----------
    if (!ownedLane) { sumS = f2s(0.f); sumP = f2s(0.f); }
    float aS = sumS.x + sumS.y;
    float aP = sumP.x + sumP.y;
#pragma unroll
    for (int off = 32; off > 0; off >>= 1) {
        aS += __shfl_down(aS, off, 64);
        aP += __shfl_down(aP, off, 64);
    }
    if (lane == 0) {
        const int base = plane * 4 + tensor * 2;
        atomicAdd(&sums[base],     aS);   // sum(skel)
        atomicAdd(&sums[base + 1], aP);   // sum(skel * other)
    }
}

__global__ void finalize_kernel(const float* __restrict__ s4, float* __restrict__ out)
{
    __shared__ float cl[32];
    int p = threadIdx.x;
    if (p < 32) {
        const float* s = s4 + p * 4;
        float tprec = s[1] / (s[0] + 1e-6f);
        float tsens = s[3] / (s[2] + 1e-6f);
        cl[p] = 2.f * tprec * tsens / (tprec + tsens + 1e-6f);
    }
    __syncthreads();
    if (p == 0) {
        float a = 0.f, vch = 0.f;
        for (int b = 0; b < 16; ++b) { a += cl[b * 2]; vch += cl[b * 2 + 1]; }
        out[0] = 1.f - 0.5f * (a / 16.f + vch / 16.f);
    }
}

extern "C" void kernel_launch(void* const* d_in, const int* in_sizes, int n_in,
                              void* d_out, int out_size, void* d_ws, size_t ws_size,
                              hipStream_t stream)
{
    const float* logits  = (const float*)d_in[0];
    const float* targets = (const float*)d_in[1];
    float* out  = (float*)d_out;
    float* sums = (float*)d_ws;

    hipMemsetAsync(d_ws, 0, 32 * 4 * sizeof(float), stream);

    // 3840 waves = 10 col-strips x 6 row-strips x 64 jobs; 4 waves per block.
    skel_kernel<<<960, 256, 0, stream>>>(logits, targets, sums);
    finalize_kernel<<<1, 64, 0, stream>>>(sums, out);
}

// Round 7
// 608.721 us; speedup vs baseline: 1.5393x; 1.1006x over previous
//
#include <hip/hip_runtime.h>
#include <math.h>

// clDice loss via register-resident temporal cascade (float2 lanes).
// All 10 soft_skel iterations run as a systolic pipeline of erode stages,
// swept top->bottom. Per lane: 2 columns (float2), per stage a 3-row rolling
// register window. No LDS, no barriers; horizontal halo via DPP wave shifts.
// R6: min/max trees as single VOP3 v_min3_f32/v_max3_f32.
// R7: 6 row-strips x 960 blocks: 510us, VALUBusy 69%, VGPR 60, no scratch.
// R8-R10 (reverted): LDS ring / body triplication / fences -> all spilled.
//   LESSON: exactly ONE copy of the hot body, no capturing-lambda bodies.
// R11: packed fp32 epilogue (VOP3P). -13% VALU instr -> dur FLAT (518us).
//   LESSON: not VALU-issue-bound. Raw capacity math: ~24% VALU util; waves
//   are stall-bound. VALUBusy counter inflated ~2.8x (gfx94x formula).
// R12: raw-defer loads. Old loadImg/loadOther applied sigmoid+edge-mask AT
//   the load site -> compiler places s_waitcnt vmcnt right after issue ->
//   every step eats full L2/LLC latency despite the "prefetch". Now loads
//   return RAW bits into registers; sigmoid/masking happen at the NEXT
//   step (img) / NEXT macro (other-ring staging rawO[3]) -> waitcnt lands
//   >=1 step after issue, giving genuine latency slack. Same ops, same
//   values (sigmoid still applied exactly once per loaded row), +6 VGPR.
//   (R12 bench run died in infra — container failure, no data. This is an
//   unchanged resubmit.)
//
// Geometry: wave covers 128 cols (lane*2 + 104*s - 12), owns 104 [104s,..).
// 10 col-strips x 6 row-strips(171 rows, 11-row warmup / 12-row drain)
// x 64 jobs (= 2 tensors x 16 batch x 2 ch) = 3840 waves = 960 blocks.

#define HH 1024
#define WW 1024
#define OWN_W 104
#define SROWS 171   // row strip height; y0 = v*171, last strip = 169 rows
#define NMACRO 65   // 195 steps = 171 + 11 warmup + 12 drain + 1 pad

#define MOD3(x) ((((x) % 3) + 3) % 3)

typedef float v2f __attribute__((ext_vector_type(2)));

__device__ __forceinline__ float2 f2s(float v) { float2 r; r.x = v; r.y = v; return r; }
__device__ __forceinline__ float sigm(float x) { return __builtin_amdgcn_rcpf(1.0f + __expf(-x)); }

// single-instruction VOP3 3-operand min/max (no IEEE canonicalize padding)
__device__ __forceinline__ float vmin3(float a, float b, float c) {
    float d; asm("v_min3_f32 %0, %1, %2, %3" : "=v"(d) : "v"(a), "v"(b), "v"(c)); return d;
}
__device__ __forceinline__ float vmax3(float a, float b, float c) {
    float d; asm("v_max3_f32 %0, %1, %2, %3" : "=v"(d) : "v"(a), "v"(b), "v"(c)); return d;
}
__device__ __forceinline__ float vmax(float a, float b) {
    float d; asm("v_max_f32 %0, %1, %2" : "=v"(d) : "v"(a), "v"(b)); return d;
}
__device__ __forceinline__ float relu(float x) {
    float d; asm("v_max_f32 %0, 0, %1" : "=v"(d) : "v"(x)); return d;
}
__device__ __forceinline__ float min5(float a, float b, float c, float d, float e) {
    return vmin3(vmin3(a, b, c), d, e);
}

// ---- VOP3P packed fp32: one instruction, two lanes of work ----
__device__ __forceinline__ float2 pk_sub(float2 a, float2 b) {   // a - b
    v2f av = {a.x, a.y}, bv = {b.x, b.y}, dv;
    asm("v_pk_add_f32 %0, %1, %2 neg_lo:[0,1] neg_hi:[0,1]"
        : "=v"(dv) : "v"(av), "v"(bv));
    float2 r; r.x = dv.x; r.y = dv.y; return r;
}
__device__ __forceinline__ float2 pk_add(float2 a, float2 b) {   // a + b
    v2f av = {a.x, a.y}, bv = {b.x, b.y}, dv;
    asm("v_pk_add_f32 %0, %1, %2" : "=v"(dv) : "v"(av), "v"(bv));
    float2 r; r.x = dv.x; r.y = dv.y; return r;
}
__device__ __forceinline__ float2 pk_fma(float2 a, float2 b, float2 c) {  // a*b + c
    v2f av = {a.x, a.y}, bv = {b.x, b.y}, cv = {c.x, c.y}, dv;
    asm("v_pk_fma_f32 %0, %1, %2, %3" : "=v"(dv) : "v"(av), "v"(bv), "v"(cv));
    float2 r; r.x = dv.x; r.y = dv.y; return r;
}

// lane i <- lane i-1 across the full wave (== __shfl_up(x,1,64)); lane 0 keeps own.
__device__ __forceinline__ float dpp_up1(float x) {
    int i = __builtin_bit_cast(int, x);
    int r = __builtin_amdgcn_update_dpp(i, i, 0x138, 0xf, 0xf, false);  // wave_shr:1
    return __builtin_bit_cast(float, r);
}
// lane i <- lane i+1 across the full wave (== __shfl_down(x,1,64)); lane 63 keeps own.
__device__ __forceinline__ float dpp_dn1(float x) {
    int i = __builtin_bit_cast(int, x);
    int r = __builtin_amdgcn_update_dpp(i, i, 0x130, 0xf, 0xf, false);  // wave_shl:1
    return __builtin_bit_cast(float, r);
}

__global__ __launch_bounds__(256, 4)
void skel_kernel(const float* __restrict__ logits,
                 const float* __restrict__ targets,
                 float* __restrict__ sums)
{
    const int lane = threadIdx.x & 63;
    const int gwid = __builtin_amdgcn_readfirstlane(blockIdx.x * 4 + (threadIdx.x >> 6));
    const int job  = gwid / 60;          // 0..63
    const int rem  = gwid - job * 60;
    const int s    = rem % 10;           // col strip 0..9
    const int v    = rem / 10;           // row strip 0..5
    const int tensor = job >> 5;         // 0: skel(pred), 1: skel(target)
    const int plane  = job & 31;
    const size_t planeOff = (size_t)plane * (HH * WW);
    const float* __restrict__ src  = tensor ? targets : logits;   // skel source
    const float* __restrict__ osrc = tensor ? logits  : targets;  // multiplied tensor
    const bool sEdge = (s == 0) || (s == 9);

    const int colBase = OWN_W * s - 12 + lane * 2;
    const bool colOOB = (colBase < 0) || (colBase > WW - 2);      // whole-lane (even boundaries)
    const int colC = colBase < 0 ? 0 : (colBase > WW - 2 ? WW - 2 : colBase);
    const int y0  = v * SROWS;
    const int yHi = (y0 + SROWS < HH) ? (y0 + SROWS) : HH;        // runtime strip end
    const int rBase = y0 - 11;

    const int ownHi = (OWN_W * (s + 1) < WW) ? OWN_W * (s + 1) : WW;
    const bool ownedLane = (colBase >= OWN_W * s) && (colBase < ownHi);

    // E[k][slot]: stage-k erode output, 3-row rolling window. Row y lives at
    // slot (y - rBase) mod 3 (stage-independent). E[0] = source image window.
    float2 E[11][3];
#pragma unroll
    for (int k = 0; k < 11; ++k)
#pragma unroll
        for (int j = 0; j < 3; ++j) E[k][j] = f2s(INFINITY);

    // shift-register ring of 'other' rows; at macro m, slot j holds row
    // (y0 - 23 + 3m + j). Stage k, phase p reads slot 10+p-k (row = dilate row).
    float2 oring[15];
#pragma unroll
    for (int j = 0; j < 15; ++j) oring[j] = f2s(0.f);

    float2 sumS = f2s(0.f), sumP = f2s(0.f);

    // RAW loads: no VALU on the loaded value at the load site -> the
    // compiler's s_waitcnt lands at the (much later) consumption point.
    auto loadImgRaw = [&](int row) -> float2 {
        if ((unsigned)row < HH) {
            return *(const float2*)(src + planeOff + (size_t)row * WW + colC);
        }
        return f2s(INFINITY);   // out-of-image rows: erode identity (no load)
    };
    auto cookImg = [&](float2 x, int row) -> float2 {
        if ((unsigned)row < HH) {          // wave-uniform
            if (!tensor) { x.x = sigm(x.x); x.y = sigm(x.y); }
            if (sEdge && colOOB) x = f2s(INFINITY);
        }
        return x;
    };
    auto loadOtherRaw = [&](int row) -> float2 {
        int rc = row < 0 ? 0 : (row > HH - 1 ? HH - 1 : row);   // address clamp only
        return *(const float2*)(osrc + planeOff + (size_t)rc * WW + colC);
    };

    // prologue: issue raws for step 0 and for macro 0's ring rows
    float2 rawImg = loadImgRaw(rBase);
    float2 rawO[3];
#pragma unroll
    for (int j = 0; j < 3; ++j) rawO[j] = loadOtherRaw(rBase + j);

#pragma unroll 1
    for (int m = 0; m < NMACRO; ++m) {
        // ring shift
#pragma unroll
        for (int j = 0; j < 12; ++j) oring[j] = oring[j + 3];
        // cook raws issued LAST macro (rows rBase+3m+j) into slots 12-14
        // (sigmoid applied exactly once per row, values identical to R11)
#pragma unroll
        for (int j = 0; j < 3; ++j) {
            float2 o = rawO[j];
            if (tensor) { o.x = sigm(o.x); o.y = sigm(o.y); }
            oring[12 + j] = o;
        }
        // issue NEXT macro's raw ring loads (consumed >= 3 steps from now)
#pragma unroll
        for (int j = 0; j < 3; ++j) rawO[j] = loadOtherRaw(rBase + 3 * (m + 1) + j);

#pragma unroll
        for (int p = 0; p < 3; ++p) {
            const int r = rBase + 3 * m + p;     // img row fed this step
            const float2 img = cookImg(rawImg, r);   // waitcnt lands HERE (1 step after issue)
            rawImg = loadImgRaw(r + 1);              // issue next step's raw row

            // ---------- Pass D: dilate stage k at row yd = r-k-2 (pre-update windows) ----------
#pragma unroll
            for (int k = 1; k <= 10; ++k) {
                const int yd = r - k - 2;
                if (yd >= y0 && yd < yHi) {             // wave-uniform ownership guard
                    const float2 a = E[k][MOD3(p - k)];       // row yd-1
                    const float2 b = E[k][MOD3(p - k + 1)];   // row yd
                    const float2 c = E[k][MOD3(p - k + 2)];   // row yd+1
                    float2 vm;
                    if (yd == 0) {                // image top: exclude row -1
                        vm.x = vmax(b.x, c.x); vm.y = vmax(b.y, c.y);
                    } else if (yd == HH - 1) {    // image bottom: exclude row 1024
                        vm.x = vmax(a.x, b.x); vm.y = vmax(a.y, b.y);
                    } else {
                        vm.x = vmax3(a.x, b.x, c.x); vm.y = vmax3(a.y, b.y, c.y);
                    }
                    if (sEdge) { if (colOOB) vm = f2s(-INFINITY); }  // col truncation at image edge
                    const float vl = dpp_up1(vm.y);
                    const float vr = dpp_dn1(vm.x);
                    float2 h;
                    h.x = vmax3(vl,   vm.x, vm.y);
                    h.y = vmax3(vm.x, vm.y, vr);
                    const float2 io = E[k - 1][MOD3(p - k + 1)];  // img_k at row yd
                    // packed epilogue: ct = relu(io - h); sumS += ct; sumP += ot*ct
                    const float2 d_ = pk_sub(io, h);
                    float2 ct;
                    ct.x = relu(d_.x);
                    ct.y = relu(d_.y);
                    const float2 ot = oring[10 + p - k];
                    sumS = pk_add(sumS, ct);
                    sumP = pk_fma(ot, ct, sumP);
                }
            }

            // ---------- Pass E: erode cascade, stage k emits row r-k ----------
            E[0][MOD3(p)] = img;
            float2 np_ = img;    // new row of stage k-1 (row r-k+1 when at stage k)
#pragma unroll
            for (int k = 1; k <= 10; ++k) {
                const float2 A = E[k - 1][MOD3(p - k + 2)];  // row r-k-1 (up)
                const float2 B = E[k - 1][MOD3(p - k)];      // row r-k   (center)
                const float2 C = np_;                        // row r-k+1 (down)
                const float bl = dpp_up1(B.y);
                const float br = dpp_dn1(B.x);
                float2 ne;
                ne.x = min5(A.x, C.x, bl,  B.y, B.x);
                ne.y = min5(A.y, C.y, B.x, br,  B.y);
                const int yN = r - k;
                if ((unsigned)yN >= HH) {        // out-of-image rows stay +inf
                    ne = f2s(INFINITY);
                } else if (sEdge) {
                    if (colOOB) ne = f2s(INFINITY);  // out-of-image cols stay +inf
                }
                E[k][MOD3(p - k)] = ne;
                np_ = ne;
            }
        }
    }

    // ---------- reduce: mask unowned lanes, wave-reduce, 2 atomics ----------
    if (!ownedLane) { sumS = f2s(0.f); sumP = f2s(0.f); }
    float aS = sumS.x + sumS.y;
    float aP = sumP.x + sumP.y;
#pragma unroll
    for (int off = 32; off > 0; off >>= 1) {
        aS += __shfl_down(aS, off, 64);
        aP += __shfl_down(aP, off, 64);
    }
    if (lane == 0) {
        const int base = plane * 4 + tensor * 2;
        atomicAdd(&sums[base],     aS);   // sum(skel)
        atomicAdd(&sums[base + 1], aP);   // sum(skel * other)
    }
}

__global__ void finalize_kernel(const float* __restrict__ s4, float* __restrict__ out)
{
    __shared__ float cl[32];
    int p = threadIdx.x;
    if (p < 32) {
        const float* s = s4 + p * 4;
        float tprec = s[1] / (s[0] + 1e-6f);
        float tsens = s[3] / (s[2] + 1e-6f);
        cl[p] = 2.f * tprec * tsens / (tprec + tsens + 1e-6f);
    }
    __syncthreads();
    if (p == 0) {
        float a = 0.f, vch = 0.f;
        for (int b = 0; b < 16; ++b) { a += cl[b * 2]; vch += cl[b * 2 + 1]; }
        out[0] = 1.f - 0.5f * (a / 16.f + vch / 16.f);
    }
}

extern "C" void kernel_launch(void* const* d_in, const int* in_sizes, int n_in,
                              void* d_out, int out_size, void* d_ws, size_t ws_size,
                              hipStream_t stream)
{
    const float* logits  = (const float*)d_in[0];
    const float* targets = (const float*)d_in[1];
    float* out  = (float*)d_out;
    float* sums = (float*)d_ws;

    hipMemsetAsync(d_ws, 0, 32 * 4 * sizeof(float), stream);

    // 3840 waves = 10 col-strips x 6 row-strips x 64 jobs; 4 waves per block.
    skel_kernel<<<960, 256, 0, stream>>>(logits, targets, sums);
    finalize_kernel<<<1, 64, 0, stream>>>(sums, out);
}

// Round 8
// 605.252 us; speedup vs baseline: 1.5481x; 1.0057x over previous
//
#include <hip/hip_runtime.h>
#include <math.h>

// clDice loss via register-resident temporal cascade (float2 lanes).
// All 10 soft_skel iterations run as a systolic pipeline of erode stages,
// swept top->bottom. Per lane: 2 columns (float2), per stage a 3-row rolling
// register window. No LDS, no barriers; horizontal halo via DPP wave shifts.
// R6: min/max trees as single VOP3 v_min3_f32/v_max3_f32.
// R7: 6 row-strips x 960 blocks: 510us, VGPR 60, no scratch.
// R8-R10 (reverted): LDS ring / body triplication / fences -> all spilled.
//   LESSON: exactly ONE copy of the hot body, no capturing-lambda bodies.
// R11: packed fp32 epilogue (VOP3P). -13% VALU instr -> dur FLAT (518us).
//   LESSON: not VALU-issue-bound; ~27% real VALU util (VALUBusy inflated
//   ~2.8x by gfx94x fallback formula). Waves are stall-bound.
// R12: raw-defer loads (sigmoid/mask at consumption, not at load site):
//   518 -> 457us. CONFIRMED wait-at-load mechanism. Residual: issue-to-wait
//   distance is ~1 step of the wave's OWN issue (~450 cyc) < HBM latency
//   (~900 cyc; FETCH 290MB ~= full inputs miss L3) -> ~450 cyc stall/step.
// R13: img prefetch depth 2 (rawImgA/rawImgB pipeline): issue-to-wait
//   distance ~2 steps (~900-1000 own-issue cyc) covers HBM latency.
//   oring staging already 3 steps deep (covered). +2 VGPR, single body.
//
// Geometry: wave covers 128 cols (lane*2 + 104*s - 12), owns 104 [104s,..).
// 10 col-strips x 6 row-strips(171 rows, 11-row warmup / 12-row drain)
// x 64 jobs (= 2 tensors x 16 batch x 2 ch) = 3840 waves = 960 blocks.

#define HH 1024
#define WW 1024
#define OWN_W 104
#define SROWS 171   // row strip height; y0 = v*171, last strip = 169 rows
#define NMACRO 65   // 195 steps = 171 + 11 warmup + 12 drain + 1 pad

#define MOD3(x) ((((x) % 3) + 3) % 3)

typedef float v2f __attribute__((ext_vector_type(2)));

__device__ __forceinline__ float2 f2s(float v) { float2 r; r.x = v; r.y = v; return r; }
__device__ __forceinline__ float sigm(float x) { return __builtin_amdgcn_rcpf(1.0f + __expf(-x)); }

// single-instruction VOP3 3-operand min/max (no IEEE canonicalize padding)
__device__ __forceinline__ float vmin3(float a, float b, float c) {
    float d; asm("v_min3_f32 %0, %1, %2, %3" : "=v"(d) : "v"(a), "v"(b), "v"(c)); return d;
}
__device__ __forceinline__ float vmax3(float a, float b, float c) {
    float d; asm("v_max3_f32 %0, %1, %2, %3" : "=v"(d) : "v"(a), "v"(b), "v"(c)); return d;
}
__device__ __forceinline__ float vmax(float a, float b) {
    float d; asm("v_max_f32 %0, %1, %2" : "=v"(d) : "v"(a), "v"(b)); return d;
}
__device__ __forceinline__ float relu(float x) {
    float d; asm("v_max_f32 %0, 0, %1" : "=v"(d) : "v"(x)); return d;
}
__device__ __forceinline__ float min5(float a, float b, float c, float d, float e) {
    return vmin3(vmin3(a, b, c), d, e);
}

// ---- VOP3P packed fp32: one instruction, two lanes of work ----
__device__ __forceinline__ float2 pk_sub(float2 a, float2 b) {   // a - b
    v2f av = {a.x, a.y}, bv = {b.x, b.y}, dv;
    asm("v_pk_add_f32 %0, %1, %2 neg_lo:[0,1] neg_hi:[0,1]"
        : "=v"(dv) : "v"(av), "v"(bv));
    float2 r; r.x = dv.x; r.y = dv.y; return r;
}
__device__ __forceinline__ float2 pk_add(float2 a, float2 b) {   // a + b
    v2f av = {a.x, a.y}, bv = {b.x, b.y}, dv;
    asm("v_pk_add_f32 %0, %1, %2" : "=v"(dv) : "v"(av), "v"(bv));
    float2 r; r.x = dv.x; r.y = dv.y; return r;
}
__device__ __forceinline__ float2 pk_fma(float2 a, float2 b, float2 c) {  // a*b + c
    v2f av = {a.x, a.y}, bv = {b.x, b.y}, cv = {c.x, c.y}, dv;
    asm("v_pk_fma_f32 %0, %1, %2, %3" : "=v"(dv) : "v"(av), "v"(bv), "v"(cv));
    float2 r; r.x = dv.x; r.y = dv.y; return r;
}

// lane i <- lane i-1 across the full wave (== __shfl_up(x,1,64)); lane 0 keeps own.
__device__ __forceinline__ float dpp_up1(float x) {
    int i = __builtin_bit_cast(int, x);
    int r = __builtin_amdgcn_update_dpp(i, i, 0x138, 0xf, 0xf, false);  // wave_shr:1
    return __builtin_bit_cast(float, r);
}
// lane i <- lane i+1 across the full wave (== __shfl_down(x,1,64)); lane 63 keeps own.
__device__ __forceinline__ float dpp_dn1(float x) {
    int i = __builtin_bit_cast(int, x);
    int r = __builtin_amdgcn_update_dpp(i, i, 0x130, 0xf, 0xf, false);  // wave_shl:1
    return __builtin_bit_cast(float, r);
}

__global__ __launch_bounds__(256, 4)
void skel_kernel(const float* __restrict__ logits,
                 const float* __restrict__ targets,
                 float* __restrict__ sums)
{
    const int lane = threadIdx.x & 63;
    const int gwid = __builtin_amdgcn_readfirstlane(blockIdx.x * 4 + (threadIdx.x >> 6));
    const int job  = gwid / 60;          // 0..63
    const int rem  = gwid - job * 60;
    const int s    = rem % 10;           // col strip 0..9
    const int v    = rem / 10;           // row strip 0..5
    const int tensor = job >> 5;         // 0: skel(pred), 1: skel(target)
    const int plane  = job & 31;
    const size_t planeOff = (size_t)plane * (HH * WW);
    const float* __restrict__ src  = tensor ? targets : logits;   // skel source
    const float* __restrict__ osrc = tensor ? logits  : targets;  // multiplied tensor
    const bool sEdge = (s == 0) || (s == 9);

    const int colBase = OWN_W * s - 12 + lane * 2;
    const bool colOOB = (colBase < 0) || (colBase > WW - 2);      // whole-lane (even boundaries)
    const int colC = colBase < 0 ? 0 : (colBase > WW - 2 ? WW - 2 : colBase);
    const int y0  = v * SROWS;
    const int yHi = (y0 + SROWS < HH) ? (y0 + SROWS) : HH;        // runtime strip end
    const int rBase = y0 - 11;

    const int ownHi = (OWN_W * (s + 1) < WW) ? OWN_W * (s + 1) : WW;
    const bool ownedLane = (colBase >= OWN_W * s) && (colBase < ownHi);

    // E[k][slot]: stage-k erode output, 3-row rolling window. Row y lives at
    // slot (y - rBase) mod 3 (stage-independent). E[0] = source image window.
    float2 E[11][3];
#pragma unroll
    for (int k = 0; k < 11; ++k)
#pragma unroll
        for (int j = 0; j < 3; ++j) E[k][j] = f2s(INFINITY);

    // shift-register ring of 'other' rows; at macro m, slot j holds row
    // (y0 - 23 + 3m + j). Stage k, phase p reads slot 10+p-k (row = dilate row).
    float2 oring[15];
#pragma unroll
    for (int j = 0; j < 15; ++j) oring[j] = f2s(0.f);

    float2 sumS = f2s(0.f), sumP = f2s(0.f);

    // RAW loads: no VALU on the loaded value at the load site -> the
    // compiler's s_waitcnt lands at the (much later) consumption point.
    auto loadImgRaw = [&](int row) -> float2 {
        if ((unsigned)row < HH) {
            return *(const float2*)(src + planeOff + (size_t)row * WW + colC);
        }
        return f2s(INFINITY);   // out-of-image rows: erode identity (no load)
    };
    auto cookImg = [&](float2 x, int row) -> float2 {
        if ((unsigned)row < HH) {          // wave-uniform
            if (!tensor) { x.x = sigm(x.x); x.y = sigm(x.y); }
            if (sEdge && colOOB) x = f2s(INFINITY);
        }
        return x;
    };
    auto loadOtherRaw = [&](int row) -> float2 {
        int rc = row < 0 ? 0 : (row > HH - 1 ? HH - 1 : row);   // address clamp only
        return *(const float2*)(osrc + planeOff + (size_t)rc * WW + colC);
    };

    // prologue: 2-deep img pipeline + macro 0's ring rows
    float2 rawImgA = loadImgRaw(rBase);       // row for step 0
    float2 rawImgB = loadImgRaw(rBase + 1);   // row for step 1
    float2 rawO[3];
#pragma unroll
    for (int j = 0; j < 3; ++j) rawO[j] = loadOtherRaw(rBase + j);

#pragma unroll 1
    for (int m = 0; m < NMACRO; ++m) {
        // ring shift
#pragma unroll
        for (int j = 0; j < 12; ++j) oring[j] = oring[j + 3];
        // cook raws issued LAST macro (rows rBase+3m+j) into slots 12-14
        // (sigmoid applied exactly once per row, values identical to R11)
#pragma unroll
        for (int j = 0; j < 3; ++j) {
            float2 o = rawO[j];
            if (tensor) { o.x = sigm(o.x); o.y = sigm(o.y); }
            oring[12 + j] = o;
        }
        // issue NEXT macro's raw ring loads (consumed >= 3 steps from now)
#pragma unroll
        for (int j = 0; j < 3; ++j) rawO[j] = loadOtherRaw(rBase + 3 * (m + 1) + j);

#pragma unroll
        for (int p = 0; p < 3; ++p) {
            const int r = rBase + 3 * m + p;     // img row fed this step
            const float2 img = cookImg(rawImgA, r);  // waitcnt: load issued 2 steps ago
            rawImgA = rawImgB;                       // pipeline shift (renamed away)
            rawImgB = loadImgRaw(r + 2);             // issue row for step t+2

            // ---------- Pass D: dilate stage k at row yd = r-k-2 (pre-update windows) ----------
#pragma unroll
            for (int k = 1; k <= 10; ++k) {
                const int yd = r - k - 2;
                if (yd >= y0 && yd < yHi) {             // wave-uniform ownership guard
                    const float2 a = E[k][MOD3(p - k)];       // row yd-1
                    const float2 b = E[k][MOD3(p - k + 1)];   // row yd
                    const float2 c = E[k][MOD3(p - k + 2)];   // row yd+1
                    float2 vm;
                    if (yd == 0) {                // image top: exclude row -1
                        vm.x = vmax(b.x, c.x); vm.y = vmax(b.y, c.y);
                    } else if (yd == HH - 1) {    // image bottom: exclude row 1024
                        vm.x = vmax(a.x, b.x); vm.y = vmax(a.y, b.y);
                    } else {
                        vm.x = vmax3(a.x, b.x, c.x); vm.y = vmax3(a.y, b.y, c.y);
                    }
                    if (sEdge) { if (colOOB) vm = f2s(-INFINITY); }  // col truncation at image edge
                    const float vl = dpp_up1(vm.y);
                    const float vr = dpp_dn1(vm.x);
                    float2 h;
                    h.x = vmax3(vl,   vm.x, vm.y);
                    h.y = vmax3(vm.x, vm.y, vr);
                    const float2 io = E[k - 1][MOD3(p - k + 1)];  // img_k at row yd
                    // packed epilogue: ct = relu(io - h); sumS += ct; sumP += ot*ct
                    const float2 d_ = pk_sub(io, h);
                    float2 ct;
                    ct.x = relu(d_.x);
                    ct.y = relu(d_.y);
                    const float2 ot = oring[10 + p - k];
                    sumS = pk_add(sumS, ct);
                    sumP = pk_fma(ot, ct, sumP);
                }
            }

            // ---------- Pass E: erode cascade, stage k emits row r-k ----------
            E[0][MOD3(p)] = img;
            float2 np_ = img;    // new row of stage k-1 (row r-k+1 when at stage k)
#pragma unroll
            for (int k = 1; k <= 10; ++k) {
                const float2 A = E[k - 1][MOD3(p - k + 2)];  // row r-k-1 (up)
                const float2 B = E[k - 1][MOD3(p - k)];      // row r-k   (center)
                const float2 C = np_;                        // row r-k+1 (down)
                const float bl = dpp_up1(B.y);
                const float br = dpp_dn1(B.x);
                float2 ne;
                ne.x = min5(A.x, C.x, bl,  B.y, B.x);
                ne.y = min5(A.y, C.y, B.x, br,  B.y);
                const int yN = r - k;
                if ((unsigned)yN >= HH) {        // out-of-image rows stay +inf
                    ne = f2s(INFINITY);
                } else if (sEdge) {
                    if (colOOB) ne = f2s(INFINITY);  // out-of-image cols stay +inf
                }
                E[k][MOD3(p - k)] = ne;
                np_ = ne;
            }
        }
    }

    // ---------- reduce: mask unowned lanes, wave-reduce, 2 atomics ----------
    if (!ownedLane) { sumS = f2s(0.f); sumP = f2s(0.f); }
    float aS = sumS.x + sumS.y;
    float aP = sumP.x + sumP.y;
#pragma unroll
    for (int off = 32; off > 0; off >>= 1) {
        aS += __shfl_down(aS, off, 64);
        aP += __shfl_down(aP, off, 64);
    }
    if (lane == 0) {
        const int base = plane * 4 + tensor * 2;
        atomicAdd(&sums[base],     aS);   // sum(skel)
        atomicAdd(&sums[base + 1], aP);   // sum(skel * other)
    }
}

__global__ void finalize_kernel(const float* __restrict__ s4, float* __restrict__ out)
{
    __shared__ float cl[32];
    int p = threadIdx.x;
    if (p < 32) {
        const float* s = s4 + p * 4;
        float tprec = s[1] / (s[0] + 1e-6f);
        float tsens = s[3] / (s[2] + 1e-6f);
        cl[p] = 2.f * tprec * tsens / (tprec + tsens + 1e-6f);
    }
    __syncthreads();
    if (p == 0) {
        float a = 0.f, vch = 0.f;
        for (int b = 0; b < 16; ++b) { a += cl[b * 2]; vch += cl[b * 2 + 1]; }
        out[0] = 1.f - 0.5f * (a / 16.f + vch / 16.f);
    }
}

extern "C" void kernel_launch(void* const* d_in, const int* in_sizes, int n_in,
                              void* d_out, int out_size, void* d_ws, size_t ws_size,
                              hipStream_t stream)
{
    const float* logits  = (const float*)d_in[0];
    const float* targets = (const float*)d_in[1];
    float* out  = (float*)d_out;
    float* sums = (float*)d_ws;

    hipMemsetAsync(d_ws, 0, 32 * 4 * sizeof(float), stream);

    // 3840 waves = 10 col-strips x 6 row-strips x 64 jobs; 4 waves per block.
    skel_kernel<<<960, 256, 0, stream>>>(logits, targets, sums);
    finalize_kernel<<<1, 64, 0, stream>>>(sums, out);
}